// Round 2
// baseline (388.345 us; speedup 1.0000x reference)
//
#include <hip/hip_runtime.h>
#include <hip/hip_bf16.h>

// Head-axis-softmax SDPA, B=2 S=2048 N=16 D=64, fp32 in/out.
// softmax over HEADS (n) -> local per (b,q,k).
//
// R6: two-pass factorization. R5's counters (MfmaUtil 6.4, VALU 23, HBM 9%,
// 0 bank conflicts, no change from pipelining) showed the 16-wave lockstep
// cooperative structure itself was the ceiling: every pipe is phase-aligned
// across all resident waves, so nothing overlaps.
//   pass 1: Z[b,q,k] = sum_n exp2(s_n)  -- one wave per 32x32 (q,k) tile,
//           16-head loop entirely in registers (identical MFMA C-layout per
//           head => head-sum is pure VALU). No LDS, no barriers.
//           Stores Zr = mask ? 1/Z : NaN (f32) to workspace.
//   pass 2: per (b, head, q-tile): QK^T again, w = exp2(s)*zr, bf16 W via a
//           wave-private (no-barrier) LDS transpose, PV MFMA. 4 waves split
//           the k-range; partials combined once via LDS at the end ->
//           direct coalesced stores (no atomics, no memset).
// Pre-passes unchanged from R4 (Q pre-scaled by 1/8*log2e).

#define B_ 2
#define S_ 2048
#define N_ 16
#define D_ 64
#define TQ 32
#define TK 32

typedef __bf16 bf16x4 __attribute__((ext_vector_type(4)));
typedef __bf16 bf16x8 __attribute__((ext_vector_type(8)));
typedef float  f32x16 __attribute__((ext_vector_type(16)));

#define PK 40  // W-tile row stride (bf16): 80 B, 16B-aligned, low-conflict

// scale folded into Q at conversion: 1/sqrt(64) * log2(e)
#define QSCALE 0.18033688011112042f

// ---------------------------------------------------------------------------
// Pre-pass 1: Q,K [b,s,n,d] f32 -> [b,n,s,d] bf16. Both sides coalesced.
// Q additionally pre-scaled by QSCALE so main kernels use exp2 directly.
// ---------------------------------------------------------------------------
__global__ __launch_bounds__(256) void cvt_qk_kernel(
    const float* __restrict__ Qf, const float* __restrict__ Kf,
    __bf16* __restrict__ Qb, __bf16* __restrict__ Kb)
{
    const int z = blockIdx.z;                  // 0..2B-1: first B -> Q, rest -> K
    const float* src = (z < B_) ? Qf : Kf;
    __bf16*      dst = (z < B_) ? Qb : Kb;
    const float scale = (z < B_) ? QSCALE : 1.0f;
    const int b = (z < B_) ? z : z - B_;
    const int n = blockIdx.y;
    const int t = threadIdx.x;
    const int d4 = (t & 15) * 4;
    const int s  = blockIdx.x * 16 + (t >> 4);

    const float4 v = *(const float4*)&src[(((size_t)b * S_ + s) * N_ + n) * D_ + d4];
    bf16x4 o;
    o[0] = (__bf16)(v.x * scale); o[1] = (__bf16)(v.y * scale);
    o[2] = (__bf16)(v.z * scale); o[3] = (__bf16)(v.w * scale);
    *(bf16x4*)&dst[(((size_t)b * N_ + n) * S_ + s) * D_ + d4] = o;
}

// ---------------------------------------------------------------------------
// Pre-pass 2: V [b,s,n,d] f32 -> [b,n,d,s] bf16 (d<->s transpose via LDS tile).
// ---------------------------------------------------------------------------
__global__ __launch_bounds__(256) void cvt_v_kernel(
    const float* __restrict__ V, __bf16* __restrict__ Vt)
{
    __shared__ __bf16 tile[64][68];  // +4 pad breaks bank aliasing
    const int s0 = blockIdx.x * 64;
    const int n  = blockIdx.y;
    const int b  = blockIdx.z;
    const int t  = threadIdx.x;

    {
        const int d4 = (t & 15) * 4;
        const int sr = t >> 4;
        #pragma unroll
        for (int r = 0; r < 4; ++r) {
            const int s = sr + r * 16;
            const float4 v = *(const float4*)&V[(((size_t)b * S_ + s0 + s) * N_ + n) * D_ + d4];
            tile[s][d4 + 0] = (__bf16)v.x;
            tile[s][d4 + 1] = (__bf16)v.y;
            tile[s][d4 + 2] = (__bf16)v.z;
            tile[s][d4 + 3] = (__bf16)v.w;
        }
    }
    __syncthreads();
    {
        const int s4 = (t & 15) * 4;
        const int dr = t >> 4;
        #pragma unroll
        for (int r = 0; r < 4; ++r) {
            const int d = dr + r * 16;
            bf16x4 o;
            o[0] = tile[s4 + 0][d];
            o[1] = tile[s4 + 1][d];
            o[2] = tile[s4 + 2][d];
            o[3] = tile[s4 + 3][d];
            *(bf16x4*)&Vt[(((size_t)b * N_ + n) * D_ + d) * S_ + s0 + s4] = o;
        }
    }
}

// ---------------------------------------------------------------------------
// Pass 1: Zr[b][q][k] = mask ? 1/sum_n exp2(s_n) : NaN.
// Block = 256 thr = 4 waves; wave w handles k-tile blockIdx.x*4+w, q-tile
// blockIdx.y. 16-head loop fully in registers: every head's 32x32 score tile
// has the SAME C-fragment layout, so the head-sum is elementwise VALU.
// No LDS, no barriers.
// ---------------------------------------------------------------------------
__global__ __launch_bounds__(256, 4) void pass1_z_kernel(
    const __bf16* __restrict__ Qb, const __bf16* __restrict__ Kb,
    const int* __restrict__ M, float* __restrict__ Zr)
{
    const int tid  = threadIdx.x;
    const int wv   = tid >> 6;
    const int lane = tid & 63;
    const int lo   = lane & 31;
    const int hi   = lane >> 5;

    const int k0 = (blockIdx.x * 4 + wv) * TK;
    const int q0 = blockIdx.y * TQ;
    const int b  = blockIdx.z;

    f32x16 zsum = {};
    for (int h = 0; h < N_; ++h) {
        const __bf16* Qh = Qb + ((size_t)b * N_ + h) * S_ * D_;
        const __bf16* Kh = Kb + ((size_t)b * N_ + h) * S_ * D_;
        bf16x8 qf[4], kf[4];
        #pragma unroll
        for (int ks = 0; ks < 4; ++ks) {
            qf[ks] = *(const bf16x8*)&Qh[(size_t)(q0 + lo) * D_ + ks * 16 + hi * 8];
            kf[ks] = *(const bf16x8*)&Kh[(size_t)(k0 + lo) * D_ + ks * 16 + hi * 8];
        }
        f32x16 s = {};
        #pragma unroll
        for (int ks = 0; ks < 4; ++ks)
            s = __builtin_amdgcn_mfma_f32_32x32x16_bf16(qf[ks], kf[ks], s, 0, 0, 0);
        // s = (q.k)/8 * log2(e)  (scale folded into Q)
        #pragma unroll
        for (int r = 0; r < 16; ++r) zsum[r] += exp2f(s[r]);
    }

    // rd = 1/Z (v_rcp_f32, ~1 ulp; bf16 W rounding dominates), fold mask.
    const size_t mb = (size_t)b * S_ * S_;
    #pragma unroll
    for (int r = 0; r < 16; ++r) {
        const int row = (r & 3) + 8 * (r >> 2) + 4 * hi;
        const size_t idx = mb + (size_t)(q0 + row) * S_ + (k0 + lo);
        const float rd = __builtin_amdgcn_rcpf(zsum[r]);
        // mask==0: ref softmax over all-(-inf) heads -> NaN weights
        Zr[idx] = M[idx] ? rd : __builtin_nanf("");
    }
}

// ---------------------------------------------------------------------------
// Pass 2: out[b,n,q,:] = sum_k (exp2(s)*zr) V[k,:]. Block = 256 thr = 4 waves,
// one (b, head, q-tile) per block; wave w sweeps k in [w*512, w*512+512).
// W transpose via wave-PRIVATE double-buffered LDS tile: no barriers in the
// k-loop. End: one LDS combine of the 4 k-partials, direct coalesced stores.
// ---------------------------------------------------------------------------
__global__ __launch_bounds__(256, 2) void pass2_av_kernel(
    const __bf16* __restrict__ Qb, const __bf16* __restrict__ Kb,
    const __bf16* __restrict__ Vt, const float* __restrict__ Zr,
    float* __restrict__ O)
{
    __shared__ __align__(16) __bf16 wbuf[4][2][TQ][PK];  // 20 KB, per-wave dbuf
    __shared__ __align__(16) float  obuf[4][TQ * D_];    // 32 KB, end combine

    const int tid  = threadIdx.x;
    const int wv   = tid >> 6;
    const int lane = tid & 63;
    const int lo   = lane & 31;
    const int hi   = lane >> 5;

    const int q0 = blockIdx.x * TQ;
    const int n  = blockIdx.y;
    const int b  = blockIdx.z;

    const __bf16* Qh = Qb + ((size_t)b * N_ + n) * S_ * D_;
    const __bf16* Kh = Kb + ((size_t)b * N_ + n) * S_ * D_;
    const __bf16* Vh = Vt + ((size_t)b * N_ + n) * D_ * S_;
    const float*  Zh = Zr + (size_t)b * S_ * S_;

    // Q A-frags (pre-scaled): one b128 per ks
    bf16x8 qf[4];
    #pragma unroll
    for (int ks = 0; ks < 4; ++ks)
        qf[ks] = *(const bf16x8*)&Qh[(size_t)(q0 + lo) * D_ + ks * 16 + hi * 8];

    f32x16 o0 = {};  // out cols d =  0..31 (C layout)
    f32x16 o1 = {};  // out cols d = 32..63

    const int kb = wv * (S_ / 4);
    #pragma unroll 2
    for (int t = 0; t < 16; ++t) {
        const int k0 = kb + t * TK;
        const int pb = t & 1;

        // zr loads (coalesced along k; L2/L3-resident) issued early
        float zr[16];
        #pragma unroll
        for (int r = 0; r < 16; ++r) {
            const int row = (r & 3) + 8 * (r >> 2) + 4 * hi;
            zr[r] = Zh[(size_t)(q0 + row) * S_ + k0 + lo];
        }

        // V B-frags (k = key, col = d=dt*32+lo)
        bf16x8 vf[2][2];
        #pragma unroll
        for (int kstep = 0; kstep < 2; ++kstep)
            #pragma unroll
            for (int dt = 0; dt < 2; ++dt)
                vf[kstep][dt] = *(const bf16x8*)&Vh[(size_t)(dt * 32 + lo) * S_
                                                   + k0 + kstep * 16 + hi * 8];

        // QK^T
        f32x16 s = {};
        #pragma unroll
        for (int ks = 0; ks < 4; ++ks) {
            bf16x8 kf = *(const bf16x8*)&Kh[(size_t)(k0 + lo) * D_ + ks * 16 + hi * 8];
            s = __builtin_amdgcn_mfma_f32_32x32x16_bf16(qf[ks], kf, s, 0, 0, 0);
        }

        // w = exp2(s) * zr -> bf16 -> wave-private LDS tile (C layout)
        #pragma unroll
        for (int r = 0; r < 16; ++r) {
            const int row = (r & 3) + 8 * (r >> 2) + 4 * hi;
            wbuf[wv][pb][row][lo] = (__bf16)(exp2f(s[r]) * zr[r]);
        }

        // PV: A = W (b128 from own tile; same-wave RAW -> compiler lgkmcnt,
        // no barrier). Double-buffered on t so next tile's writes don't WAR.
        #pragma unroll
        for (int kstep = 0; kstep < 2; ++kstep) {
            bf16x8 wf = *(const bf16x8*)&wbuf[wv][pb][lo][kstep * 16 + hi * 8];
            o0 = __builtin_amdgcn_mfma_f32_32x32x16_bf16(wf, vf[kstep][0], o0, 0, 0, 0);
            o1 = __builtin_amdgcn_mfma_f32_32x32x16_bf16(wf, vf[kstep][1], o1, 0, 0, 0);
        }
    }

    // k-split combine: each wave deposits its partial tile, one barrier,
    // then 256 threads tree-sum 4 partials and store coalesced f32x4.
    #pragma unroll
    for (int r = 0; r < 16; ++r) {
        const int row = (r & 3) + 8 * (r >> 2) + 4 * hi;
        obuf[wv][row * D_ + lo]      = o0[r];
        obuf[wv][row * D_ + 32 + lo] = o1[r];
    }
    __syncthreads();

    {
        const int e0 = tid * 8;          // 8 consecutive output f32 per thread
        float a[8] = {0, 0, 0, 0, 0, 0, 0, 0};
        #pragma unroll
        for (int w = 0; w < 4; ++w) {
            const float4 x = *(const float4*)&obuf[w][e0];
            const float4 y = *(const float4*)&obuf[w][e0 + 4];
            a[0] += x.x; a[1] += x.y; a[2] += x.z; a[3] += x.w;
            a[4] += y.x; a[5] += y.y; a[6] += y.z; a[7] += y.w;
        }
        const int q = e0 >> 6;
        const int d = e0 & 63;
        float* dst = &O[(((size_t)b * N_ + n) * S_ + q0 + q) * (size_t)D_ + d];
        *(float4*)dst       = make_float4(a[0], a[1], a[2], a[3]);
        *(float4*)(dst + 4) = make_float4(a[4], a[5], a[6], a[7]);
    }
}

// ---------------------------------------------------------------------------
// Fallback (R2 kernel, fp32 inputs): used only if ws is too small.
// ---------------------------------------------------------------------------
__global__ __launch_bounds__(1024) void sdpa_headsm_kernel(
    const float* __restrict__ Q, const float* __restrict__ K,
    const float* __restrict__ V, const int* __restrict__ M,
    float* __restrict__ O)
{
    __shared__ __align__(16) __bf16 pbuf[N_][TQ][PK];

    const int tid  = threadIdx.x;
    const int n    = tid >> 6;
    const int lane = tid & 63;
    const int lo   = lane & 31;
    const int hi   = lane >> 5;

    const int q0 = blockIdx.x * TQ;
    const int b  = blockIdx.y;
    const int kz = blockIdx.z;
    const int FITERS = S_ / TK / 4;

    bf16x8 qf[4];
    {
        const float* qrow = Q + (((size_t)b * S_ + (size_t)(q0 + lo)) * N_ + n) * D_;
        #pragma unroll
        for (int ks = 0; ks < 4; ++ks) {
            const float* p = qrow + ks * 16 + hi * 8;
            float4 a0 = *(const float4*)(p);
            float4 a1 = *(const float4*)(p + 4);
            bf16x8 f;
            f[0] = (__bf16)a0.x; f[1] = (__bf16)a0.y;
            f[2] = (__bf16)a0.z; f[3] = (__bf16)a0.w;
            f[4] = (__bf16)a1.x; f[5] = (__bf16)a1.y;
            f[6] = (__bf16)a1.z; f[7] = (__bf16)a1.w;
            qf[ks] = f;
        }
    }

    f32x16 o0 = {};
    f32x16 o1 = {};

    for (int it = 0; it < FITERS; ++it) {
        const int k0 = (kz * FITERS + it) * TK;

        f32x16 s = {};
        #pragma unroll
        for (int ks = 0; ks < 4; ++ks) {
            const float* krow = K + (((size_t)b * S_ + (size_t)(k0 + lo)) * N_ + n) * D_
                                  + ks * 16 + hi * 8;
            float4 a0 = *(const float4*)(krow);
            float4 a1 = *(const float4*)(krow + 4);
            bf16x8 f;
            f[0] = (__bf16)a0.x; f[1] = (__bf16)a0.y;
            f[2] = (__bf16)a0.z; f[3] = (__bf16)a0.w;
            f[4] = (__bf16)a1.x; f[5] = (__bf16)a1.y;
            f[6] = (__bf16)a1.z; f[7] = (__bf16)a1.w;
            s = __builtin_amdgcn_mfma_f32_32x32x16_bf16(qf[ks], f, s, 0, 0, 0);
        }

        bf16x8 vf[2][2];
        #pragma unroll
        for (int kstep = 0; kstep < 2; ++kstep) {
            #pragma unroll
            for (int dt = 0; dt < 2; ++dt) {
                bf16x8 f;
                #pragma unroll
                for (int j = 0; j < 8; ++j) {
                    const int key = k0 + kstep * 16 + hi * 8 + j;
                    f[j] = (__bf16)V[(((size_t)b * S_ + key) * N_ + n) * D_ + dt * 32 + lo];
                }
                vf[kstep][dt] = f;
            }
        }

        #pragma unroll
        for (int r = 0; r < 16; ++r) {
            const int row = (r & 3) + 8 * (r >> 2) + 4 * hi;
            pbuf[n][row][lo] = (__bf16)__expf(s[r] * 0.125f);
        }

        __syncthreads();

        {
            const int tq = tid >> 5;
            const int tk = tid & 31;
            const int m = M[(size_t)b * S_ * S_ + (size_t)(q0 + tq) * S_ + (k0 + tk)];
            float pv[16];
            float sum = 0.f;
            #pragma unroll
            for (int j = 0; j < 16; ++j) { pv[j] = (float)pbuf[j][tq][tk]; sum += pv[j]; }
            const float rd = m ? (1.0f / sum) : __builtin_nanf("");
            #pragma unroll
            for (int j = 0; j < 16; ++j) pbuf[j][tq][tk] = (__bf16)(pv[j] * rd);
        }

        __syncthreads();

        #pragma unroll
        for (int kstep = 0; kstep < 2; ++kstep) {
            bf16x8 wf = *(const bf16x8*)&pbuf[n][lo][kstep * 16 + hi * 8];
            o0 = __builtin_amdgcn_mfma_f32_32x32x16_bf16(wf, vf[kstep][0], o0, 0, 0, 0);
            o1 = __builtin_amdgcn_mfma_f32_32x32x16_bf16(wf, vf[kstep][1], o1, 0, 0, 0);
        }

        __syncthreads();
    }

    #pragma unroll
    for (int r = 0; r < 16; ++r) {
        const int row = (r & 3) + 8 * (r >> 2) + 4 * hi;
        const size_t base = (((size_t)b * N_ + n) * S_ + (q0 + row)) * (size_t)D_;
        atomicAdd(&O[base + lo],      o0[r]);
        atomicAdd(&O[base + 32 + lo], o1[r]);
    }
}

extern "C" void kernel_launch(void* const* d_in, const int* in_sizes, int n_in,
                              void* d_out, int out_size, void* d_ws, size_t ws_size,
                              hipStream_t stream) {
    const float* Q = (const float*)d_in[0];
    const float* K = (const float*)d_in[1];
    const float* V = (const float*)d_in[2];
    const int*   M = (const int*)d_in[3];
    float* O = (float*)d_out;

    const size_t per  = (size_t)B_ * N_ * S_ * D_;         // 4,194,304 elements
    const size_t zcnt = (size_t)B_ * S_ * S_;              // 8,388,608 elements
    const size_t need = 3 * per * sizeof(__bf16) + zcnt * sizeof(float);  // 56 MB

    if (ws_size >= need) {
        __bf16* Qb = (__bf16*)d_ws;
        __bf16* Kb = Qb + per;
        __bf16* Vt = Kb + per;
        float*  Zr = (float*)(Vt + per);
        cvt_qk_kernel<<<dim3(S_ / 16, N_, B_ * 2), dim3(256), 0, stream>>>(Q, K, Qb, Kb);
        cvt_v_kernel<<<dim3(S_ / 64, N_, B_), dim3(256), 0, stream>>>(V, Vt);
        pass1_z_kernel<<<dim3(S_ / TK / 4, S_ / TQ, B_), dim3(256), 0, stream>>>(Qb, Kb, M, Zr);
        pass2_av_kernel<<<dim3(S_ / TQ, N_, B_), dim3(256), 0, stream>>>(Qb, Kb, Vt, Zr, O);
    } else {
        hipMemsetAsync(d_out, 0, (size_t)out_size * sizeof(float), stream);
        sdpa_headsm_kernel<<<dim3(S_ / TQ, B_, 4), dim3(1024), 0, stream>>>(Q, K, V, M, O);
    }
}